// Round 1
// baseline (167.879 us; speedup 1.0000x reference)
//
#include <hip/hip_runtime.h>

#define BINS 10
#define TPB 256
#define VEC_ITERS 16   // float4 iterations per thread => 64 elements/thread

// Zero the 20-float accumulator area in d_ws (re-poisoned to 0xAA before each call).
__global__ __launch_bounds__(64) void ghmc_zero(float* ws) {
    if (threadIdx.x < 2 * BINS) ws[threadIdx.x] = 0.0f;
}

__device__ __forceinline__ void ghmc_accum(float z, int t, float2* acc, int tid) {
    float tf = (float)t;
    float az = fabsf(z);
    float e  = __expf(-az);                       // exp(-|z|), v_exp
    float q  = 1.0f + e;
    float r  = __builtin_amdgcn_rcpf(q);          // ~1/(1+e)
    float s  = (z >= 0.0f) ? r : e * r;           // sigmoid(z)
    float g  = fabsf(s - tf);
    int bin  = (int)(g * 9.9999f);                // g>=0 so trunc == floor
    bin = bin < (BINS - 1) ? bin : (BINS - 1);
    // ce = logaddexp(0,z) - z*t = max(z,0) + log(1+exp(-|z|)) - z*t
    float ce = fmaxf(z, 0.0f) - z * tf + __logf(q);
    int i = bin * TPB + tid;
    float2 v = acc[i];
    v.x += ce;
    v.y += 1.0f;
    acc[i] = v;
}

__global__ __launch_bounds__(TPB) void ghmc_main(const float* __restrict__ x,
                                                 const int* __restrict__ tgt,
                                                 float* __restrict__ gsum,
                                                 float* __restrict__ gcnt,
                                                 int nvec, int ntotal) {
    __shared__ float2 acc[BINS * TPB];   // 20 KB: per-thread private columns
    const int tid = threadIdx.x;
    #pragma unroll
    for (int b = 0; b < BINS; ++b) acc[b * TPB + tid] = make_float2(0.0f, 0.0f);
    // No barrier needed: each thread touches only its own column until reduction.

    const float4* __restrict__ x4 = (const float4*)x;
    const int4*  __restrict__ t4 = (const int4*)tgt;
    const int base = blockIdx.x * (TPB * VEC_ITERS) + tid;

    #pragma unroll 4
    for (int j = 0; j < VEC_ITERS; ++j) {
        int gi = base + j * TPB;
        if (gi < nvec) {
            float4 xv = x4[gi];
            int4   tv = t4[gi];
            ghmc_accum(xv.x, tv.x, acc, tid);
            ghmc_accum(xv.y, tv.y, acc, tid);
            ghmc_accum(xv.z, tv.z, acc, tid);
            ghmc_accum(xv.w, tv.w, acc, tid);
        }
    }
    // Scalar tail (N not a multiple of 4) — no-op for N = 2^24.
    if (blockIdx.x == 0) {
        for (int i = nvec * 4 + tid; i < ntotal; i += TPB) {
            ghmc_accum(x[i], tgt[i], acc, tid);
        }
    }

    __syncthreads();
    // Tree-reduce the 256 columns for each bin.
    for (int sft = TPB / 2; sft > 0; sft >>= 1) {
        if (tid < sft) {
            #pragma unroll
            for (int b = 0; b < BINS; ++b) {
                float2 a = acc[b * TPB + tid];
                float2 o = acc[b * TPB + tid + sft];
                a.x += o.x;
                a.y += o.y;
                acc[b * TPB + tid] = a;
            }
        }
        __syncthreads();
    }
    if (tid < BINS) {
        atomicAdd(&gsum[tid], acc[tid * TPB].x);
        atomicAdd(&gcnt[tid], acc[tid * TPB].y);
    }
}

// result = sum_b sum_ce_b / max(cnt_b * nonempty, 1e-6)   (the N in beta cancels)
__global__ __launch_bounds__(64) void ghmc_final(const float* __restrict__ gsum,
                                                 const float* __restrict__ gcnt,
                                                 float* __restrict__ out) {
    int t = threadIdx.x;
    float cnt = (t < BINS) ? gcnt[t] : 0.0f;
    float sum = (t < BINS) ? gsum[t] : 0.0f;
    float ne  = (cnt > 0.0f) ? 1.0f : 0.0f;
    #pragma unroll
    for (int o = 32; o > 0; o >>= 1) ne += __shfl_down(ne, o);
    ne = __shfl(ne, 0);
    float term = (t < BINS) ? sum / fmaxf(cnt * ne, 1e-6f) : 0.0f;
    #pragma unroll
    for (int o = 32; o > 0; o >>= 1) term += __shfl_down(term, o);
    if (t == 0) out[0] = term;
}

extern "C" void kernel_launch(void* const* d_in, const int* in_sizes, int n_in,
                              void* d_out, int out_size, void* d_ws, size_t ws_size,
                              hipStream_t stream) {
    const float* x   = (const float*)d_in[0];
    const int*   tgt = (const int*)d_in[1];
    float* out  = (float*)d_out;
    float* gsum = (float*)d_ws;
    float* gcnt = gsum + BINS;

    int N    = in_sizes[0];
    int nvec = N / 4;
    int blocks = (nvec + TPB * VEC_ITERS - 1) / (TPB * VEC_ITERS);
    if (blocks < 1) blocks = 1;

    ghmc_zero<<<1, 64, 0, stream>>>(gsum);
    ghmc_main<<<blocks, TPB, 0, stream>>>(x, tgt, gsum, gcnt, nvec, N);
    ghmc_final<<<1, 64, 0, stream>>>(gsum, gcnt, out);
}